// Round 20
// baseline (217.182 us; speedup 1.0000x reference)
//
#include <hip/hip_runtime.h>
#include <stdint.h>

#define Bv 8
#define Cv 64
#define Lv 65536
#define TPB 512
#define HALF 128                      // cols per half-tile
#define COLS 256                      // cols per block (2 halves)
#define BLKS_PER_B (Lv / COLS)        // 256
#define GRID1 (Bv * BLKS_PER_B)       // 2048

// workspace: partials 2*2048 floats (16 KiB) + sb 1024 floats (4 KiB) = 20 KiB

typedef __attribute__((ext_vector_type(8))) short short8;
typedef __attribute__((ext_vector_type(4))) float f32x4;

#define SSTRIDE 132   // dwords per row

__device__ __forceinline__ uint16_t f2bf(float f) {
    uint32_t u = __float_as_uint(f);
    uint32_t r = u + 0x7FFFu + ((u >> 16) & 1u);   // round-to-nearest-even
    return (uint16_t)(r >> 16);
}
__device__ __forceinline__ uint32_t pack2bf(float lo, float hi) {
    return (uint32_t)f2bf(lo) | ((uint32_t)f2bf(hi) << 16);
}
__device__ __forceinline__ float bf_lo(uint32_t u) { return __uint_as_float(u << 16); }
__device__ __forceinline__ float bf_hi(uint32_t u) { return __uint_as_float(u & 0xFFFF0000u); }

// ---------------------------------------------------------------------------
// Pass 1 (MFMA, nt=1, x-in-LDS, T14 + register budget):
//   out = relu(Wf·(x⊙(Wg·s+2bg)) + bf + resid)
// R20 theory: ALL 14 variants had VGPR_Count 40-64 — hipcc's default
// occupancy heuristic caps regalloc at 64 VGPRs, so waves never hold more
// than ~6 loads in flight (the true ~171us invariant; R11's spill streams
// accidentally proved 4 TB/s is reachable with more outstanding requests).
// R18's T14 prefetch spilled ONLY because 48 held regs don't fit in 64.
// Fix: __launch_bounds__(512,4) -> 128 VGPR budget (base~40 + acc 32 +
// T14 48 = ~120). Occupancy drops to 16 waves/CU (R13 proved wave count
// isn't the lever); per-wave MLP ~quadruples. Single variable vs R18.
// ---------------------------------------------------------------------------
__global__ __launch_bounds__(TPB, 4)
void pass1(const float* __restrict__ x, const float* __restrict__ inj0,
           const float* __restrict__ inj1, const float* __restrict__ resid,
           const float* __restrict__ gate_w, const float* __restrict__ gate_b,
           const float* __restrict__ fuse_w, const float* __restrict__ fuse_b,
           float* __restrict__ out, float* __restrict__ partials)
{
    __shared__ uint32_t s_buf[32 * SSTRIDE];   // 16.9 KB (s / acc / epi tile)
    __shared__ uint32_t x_buf[32 * SSTRIDE];   // 16.9 KB (x bf16 kpairs)
    __shared__ uint32_t w_lds[2][64][36];      // 18.4 KB
    __shared__ float cinit[2][64];             // [0]=2*gate_b, [1]=fuse_b
    __shared__ float wred[16];                 // per-wave stats partials

    const int tid  = threadIdx.x;
    const int lane = tid & 63;
    const int w    = tid >> 6;     // wave 0..7
    const int g    = lane >> 4;    // k-group 0..3
    const int ln   = lane & 15;    // 0..15
    const int n    = 16 * w + ln;  // wave's column within the half

    const int b    = blockIdx.x >> 8;
    const int lb   = blockIdx.x & 255;
    const int bCL  = b * (Cv * Lv);

    // staging geometry (per thread, 2 units)
    const int kp0 = tid >> 5;                  // unit 0 ch pair
    const int c0s = (tid & 31) << 2;           // unit 0 col offset
    const int kp1 = (tid + TPB) >> 5;          // unit 1 ch pair
    const int c1s = ((tid + TPB) & 31) << 2;   // unit 1 col offset

    // ---- stage weights + cinit (once) ----
    {
        const int mat = tid >> 8;              // 0=gate, 1=fuse
        const int m   = (tid >> 2) & 63;
        const int k0  = (tid & 3) << 4;
        const float* wsrc = mat ? fuse_w : gate_w;
        const float4* w4 = reinterpret_cast<const float4*>(wsrc + m * 64 + k0);
        uint32_t* dst = &w_lds[mat][m][k0 >> 1];
        #pragma unroll
        for (int q = 0; q < 4; ++q) {
            const float4 v = w4[q];
            dst[2 * q]     = pack2bf(v.x, v.y);
            dst[2 * q + 1] = pack2bf(v.z, v.w);
        }
        if (tid < 64) {
            cinit[0][tid] = 2.0f * gate_b[tid];
            cinit[1][tid] = fuse_b[tid];
        }
    }

    // ---- prologue: stage half 0 (load+pack+write, unavoidable stall) ----
    {
        const int col0 = lb * COLS;
        #pragma unroll
        for (int uu = 0; uu < 2; ++uu) {
            const int kp = uu ? kp1 : kp0;
            const int c  = uu ? c1s : c0s;
            const int rA = bCL + (2 * kp) * Lv + col0 + c;
            const int rB = rA + Lv;
            const float4 xA = *reinterpret_cast<const float4*>(x    + rA);
            const float4 aA = *reinterpret_cast<const float4*>(inj0 + rA);
            const float4 bA = *reinterpret_cast<const float4*>(inj1 + rA);
            const float4 xB = *reinterpret_cast<const float4*>(x    + rB);
            const float4 aB = *reinterpret_cast<const float4*>(inj0 + rB);
            const float4 bB = *reinterpret_cast<const float4*>(inj1 + rB);
            uint4 dw, dx;
            dw.x = pack2bf(aA.x + bA.x + 2.0f * xA.x, aB.x + bB.x + 2.0f * xB.x);
            dw.y = pack2bf(aA.y + bA.y + 2.0f * xA.y, aB.y + bB.y + 2.0f * xB.y);
            dw.z = pack2bf(aA.z + bA.z + 2.0f * xA.z, aB.z + bB.z + 2.0f * xB.z);
            dw.w = pack2bf(aA.w + bA.w + 2.0f * xA.w, aB.w + bB.w + 2.0f * xB.w);
            *reinterpret_cast<uint4*>(&s_buf[kp * SSTRIDE + c]) = dw;
            dx.x = pack2bf(xA.x, xB.x);
            dx.y = pack2bf(xA.y, xB.y);
            dx.z = pack2bf(xA.z, xB.z);
            dx.w = pack2bf(xA.w, xB.w);
            *reinterpret_cast<uint4*>(&x_buf[kp * SSTRIDE + c]) = dx;
        }
    }
    __syncthreads();   // s, x, weights, cinit visible

    float lsum = 0.0f, lsq = 0.0f;
    float4 L[2][6];    // T14: half-1 staged loads, held through half-0 compute

    #pragma unroll 1
    for (int h = 0; h < 2; ++h) {
        const int col0 = lb * COLS + h * HALF;

        // ---- T14 issue: half-1 loads -> regs (no use until after epi) ----
        if (h == 0) {
            const int col1 = lb * COLS + HALF;
            #pragma unroll
            for (int uu = 0; uu < 2; ++uu) {
                const int kp = uu ? kp1 : kp0;
                const int c  = uu ? c1s : c0s;
                const int rA = bCL + (2 * kp) * Lv + col1 + c;
                const int rB = rA + Lv;
                L[uu][0] = *reinterpret_cast<const float4*>(x    + rA);
                L[uu][1] = *reinterpret_cast<const float4*>(inj0 + rA);
                L[uu][2] = *reinterpret_cast<const float4*>(inj1 + rA);
                L[uu][3] = *reinterpret_cast<const float4*>(x    + rB);
                L[uu][4] = *reinterpret_cast<const float4*>(inj0 + rB);
                L[uu][5] = *reinterpret_cast<const float4*>(inj1 + rB);
            }
        }

        // ---- GEMM1: D1 = Wg . s + 2bg  (full K, 8 MFMA, 16 acc regs) ----
        f32x4 D1[4];
        #pragma unroll
        for (int oc = 0; oc < 4; ++oc) {
            const float4 cb = *reinterpret_cast<const float4*>(&cinit[0][16 * oc + 4 * g]);
            D1[oc][0] = cb.x; D1[oc][1] = cb.y; D1[oc][2] = cb.z; D1[oc][3] = cb.w;
        }
        {
            uint4 B0, B1;
            B0.x = s_buf[(4 * g + 0) * SSTRIDE + n];
            B0.y = s_buf[(4 * g + 1) * SSTRIDE + n];
            B0.z = s_buf[(4 * g + 2) * SSTRIDE + n];
            B0.w = s_buf[(4 * g + 3) * SSTRIDE + n];
            B1.x = s_buf[(16 + 4 * g + 0) * SSTRIDE + n];
            B1.y = s_buf[(16 + 4 * g + 1) * SSTRIDE + n];
            B1.z = s_buf[(16 + 4 * g + 2) * SSTRIDE + n];
            B1.w = s_buf[(16 + 4 * g + 3) * SSTRIDE + n];
            #pragma unroll
            for (int oc = 0; oc < 4; ++oc) {
                const int m = ln + 16 * oc;
                const uint4 A0 = *reinterpret_cast<const uint4*>(&w_lds[0][m][4 * g]);
                const uint4 A1 = *reinterpret_cast<const uint4*>(&w_lds[0][m][16 + 4 * g]);
                D1[oc] = __builtin_amdgcn_mfma_f32_16x16x32_bf16(
                    __builtin_bit_cast(short8, A0), __builtin_bit_cast(short8, B0),
                    D1[oc], 0, 0, 0);
                D1[oc] = __builtin_amdgcn_mfma_f32_16x16x32_bf16(
                    __builtin_bit_cast(short8, A1), __builtin_bit_cast(short8, B1),
                    D1[oc], 0, 0, 0);
            }
        }

        // ---- acc = x*g (x from LDS) -> in-place into s_buf (own slab) ----
        #pragma unroll
        for (int oc = 0; oc < 4; ++oc) {
            const int kp = 8 * oc + 2 * g;            // ch pair (16oc+4g)/2
            const uint32_t u0 = x_buf[kp * SSTRIDE + n];
            const uint32_t u1 = x_buf[(kp + 1) * SSTRIDE + n];
            float av[4];
            av[0] = bf_lo(u0) * D1[oc][0];
            av[1] = bf_hi(u0) * D1[oc][1];
            av[2] = bf_lo(u1) * D1[oc][2];
            av[3] = bf_hi(u1) * D1[oc][3];
            s_buf[kp * SSTRIDE + n]       = pack2bf(av[0], av[1]);
            s_buf[(kp + 1) * SSTRIDE + n] = pack2bf(av[2], av[3]);
        }
        __syncthreads();   // same-slab ordering safety

        // ---- GEMM2: D2 = Wf . acc + fuse_b  (full K, 8 MFMA, 16 acc regs) --
        f32x4 D2[4];
        #pragma unroll
        for (int oc = 0; oc < 4; ++oc) {
            const float4 cb = *reinterpret_cast<const float4*>(&cinit[1][16 * oc + 4 * g]);
            D2[oc][0] = cb.x; D2[oc][1] = cb.y; D2[oc][2] = cb.z; D2[oc][3] = cb.w;
        }
        {
            uint4 B0, B1;
            B0.x = s_buf[(4 * g + 0) * SSTRIDE + n];
            B0.y = s_buf[(4 * g + 1) * SSTRIDE + n];
            B0.z = s_buf[(4 * g + 2) * SSTRIDE + n];
            B0.w = s_buf[(4 * g + 3) * SSTRIDE + n];
            B1.x = s_buf[(16 + 4 * g + 0) * SSTRIDE + n];
            B1.y = s_buf[(16 + 4 * g + 1) * SSTRIDE + n];
            B1.z = s_buf[(16 + 4 * g + 2) * SSTRIDE + n];
            B1.w = s_buf[(16 + 4 * g + 3) * SSTRIDE + n];
            #pragma unroll
            for (int oc = 0; oc < 4; ++oc) {
                const int m = ln + 16 * oc;
                const uint4 A0 = *reinterpret_cast<const uint4*>(&w_lds[1][m][4 * g]);
                const uint4 A1 = *reinterpret_cast<const uint4*>(&w_lds[1][m][16 + 4 * g]);
                D2[oc] = __builtin_amdgcn_mfma_f32_16x16x32_bf16(
                    __builtin_bit_cast(short8, A0), __builtin_bit_cast(short8, B0),
                    D2[oc], 0, 0, 0);
                D2[oc] = __builtin_amdgcn_mfma_f32_16x16x32_bf16(
                    __builtin_bit_cast(short8, A1), __builtin_bit_cast(short8, B1),
                    D2[oc], 0, 0, 0);
            }
        }
        __syncthreads();   // GEMM2 B-reads done before epi overwrites s_buf

        // ---- epilogue: 2 chunks of 32 rows via s_buf re-layout ----
        {
            float* uf = reinterpret_cast<float*>(s_buf);
            const int rowin = tid >> 4;          // 0..31
            const int cl    = tid & 15;          // 16 threads x 2 float4 per row
            #pragma unroll 1
            for (int ck = 0; ck < 2; ++ck) {
                #pragma unroll
                for (int oc2 = 0; oc2 < 2; ++oc2) {
                    const int oc = 2 * ck + oc2;
                    #pragma unroll
                    for (int j = 0; j < 4; ++j)
                        uf[(16 * oc2 + 4 * g + j) * SSTRIDE + n] = D2[oc][j];
                }
                const int m   = 32 * ck + rowin;
                const int gbm = bCL + m * Lv + col0;
                const float4 ra = *reinterpret_cast<const float4*>(&resid[gbm + 4 * cl]);
                const float4 rb = *reinterpret_cast<const float4*>(&resid[gbm + 4 * cl + 64]);
                __syncthreads();
                float4 va = *reinterpret_cast<const float4*>(&uf[rowin * SSTRIDE + 4 * cl]);
                float4 vb = *reinterpret_cast<const float4*>(&uf[rowin * SSTRIDE + 4 * cl + 64]);
                va.x = fmaxf(va.x + ra.x, 0.0f); va.y = fmaxf(va.y + ra.y, 0.0f);
                va.z = fmaxf(va.z + ra.z, 0.0f); va.w = fmaxf(va.w + ra.w, 0.0f);
                vb.x = fmaxf(vb.x + rb.x, 0.0f); vb.y = fmaxf(vb.y + rb.y, 0.0f);
                vb.z = fmaxf(vb.z + rb.z, 0.0f); vb.w = fmaxf(vb.w + rb.w, 0.0f);
                *reinterpret_cast<float4*>(&out[gbm + 4 * cl])      = va;
                *reinterpret_cast<float4*>(&out[gbm + 4 * cl + 64]) = vb;
                lsum += (va.x + va.y) + (va.z + va.w) + (vb.x + vb.y) + (vb.z + vb.w);
                lsq = fmaf(va.x, va.x, lsq); lsq = fmaf(va.y, va.y, lsq);
                lsq = fmaf(va.z, va.z, lsq); lsq = fmaf(va.w, va.w, lsq);
                lsq = fmaf(vb.x, vb.x, lsq); lsq = fmaf(vb.y, vb.y, lsq);
                lsq = fmaf(vb.z, vb.z, lsq); lsq = fmaf(vb.w, vb.w, lsq);
                __syncthreads();   // chunk reads done before next writes
            }
        }

        // ---- T14 write: pack+store half-1 staged regs (vmcnt drained) ----
        if (h == 0) {
            #pragma unroll
            for (int uu = 0; uu < 2; ++uu) {
                const int kp = uu ? kp1 : kp0;
                const int c  = uu ? c1s : c0s;
                const float4 xA = L[uu][0], aA = L[uu][1], bA = L[uu][2];
                const float4 xB = L[uu][3], aB = L[uu][4], bB = L[uu][5];
                uint4 dw, dx;
                dw.x = pack2bf(aA.x + bA.x + 2.0f * xA.x, aB.x + bB.x + 2.0f * xB.x);
                dw.y = pack2bf(aA.y + bA.y + 2.0f * xA.y, aB.y + bB.y + 2.0f * xB.y);
                dw.z = pack2bf(aA.z + bA.z + 2.0f * xA.z, aB.z + bB.z + 2.0f * xB.z);
                dw.w = pack2bf(aA.w + bA.w + 2.0f * xA.w, aB.w + bB.w + 2.0f * xB.w);
                *reinterpret_cast<uint4*>(&s_buf[kp * SSTRIDE + c]) = dw;
                dx.x = pack2bf(xA.x, xB.x);
                dx.y = pack2bf(xA.y, xB.y);
                dx.z = pack2bf(xA.z, xB.z);
                dx.w = pack2bf(xA.w, xB.w);
                *reinterpret_cast<uint4*>(&x_buf[kp * SSTRIDE + c]) = dx;
            }
            __syncthreads();   // half-1 s/x visible before its GEMM1
        }
    }

    // ---- stats: wave shuffle reduce -> 8 partials -> thread 0 ----
    #pragma unroll
    for (int st = 1; st < 64; st <<= 1) {
        lsum += __shfl_xor(lsum, st);
        lsq  += __shfl_xor(lsq,  st);
    }
    if (lane == 0) { wred[2 * w] = lsum; wred[2 * w + 1] = lsq; }
    __syncthreads();
    if (tid == 0) {
        float s = 0.0f, q = 0.0f;
        #pragma unroll
        for (int i = 0; i < 8; ++i) { s += wred[2 * i]; q += wred[2 * i + 1]; }
        partials[2 * blockIdx.x]     = s;
        partials[2 * blockIdx.x + 1] = q;
    }
}

// ---------------------------------------------------------------------------
// Pass 2: reduce 256 partials per batch -> per-(b,c) scale/bias.
// ---------------------------------------------------------------------------
__global__ __launch_bounds__(256)
void pass2(const float* __restrict__ partials, const float* __restrict__ gn_w,
           const float* __restrict__ gn_b, float* __restrict__ sb)
{
    __shared__ float r1[256], r2[256];
    __shared__ float mean_s, rs_s;
    const int b = blockIdx.x, tid = threadIdx.x;
    r1[tid] = partials[2 * (b * 256 + tid)];
    r2[tid] = partials[2 * (b * 256 + tid) + 1];
    __syncthreads();
    #pragma unroll
    for (int st = 128; st > 0; st >>= 1) {
        if (tid < st) { r1[tid] += r1[tid + st]; r2[tid] += r2[tid + st]; }
        __syncthreads();
    }
    if (tid == 0) {
        const float n = (float)Cv * (float)Lv;
        const float mean = r1[0] / n;
        const float var  = r2[0] / n - mean * mean;
        mean_s = mean;
        rs_s   = rsqrtf(var + 1e-5f);
    }
    __syncthreads();
    if (tid < Cv) {
        const float sc = gn_w[tid] * rs_s;
        sb[b * Cv + tid]           = sc;
        sb[Bv * Cv + b * Cv + tid] = fmaf(-mean_s, sc, gn_b[tid]);
    }
}

// ---------------------------------------------------------------------------
// Pass 3: in-place GroupNorm affine on d_out (float4 vectorized).
// ---------------------------------------------------------------------------
__global__ __launch_bounds__(256)
void pass3(float* __restrict__ out, const float* __restrict__ sb)
{
    const int total4 = (Bv * Cv * Lv) / 4;   // 8388608
    for (int i = blockIdx.x * blockDim.x + threadIdx.x; i < total4;
         i += gridDim.x * blockDim.x) {
        const int row = i >> 14;            // / (L/4): row = b*64 + c
        const float sc = sb[row];
        const float bi = sb[Bv * Cv + row];
        float4 v = reinterpret_cast<float4*>(out)[i];
        v.x = fmaf(v.x, sc, bi);
        v.y = fmaf(v.y, sc, bi);
        v.z = fmaf(v.z, sc, bi);
        v.w = fmaf(v.w, sc, bi);
        reinterpret_cast<float4*>(out)[i] = v;
    }
}

extern "C" void kernel_launch(void* const* d_in, const int* in_sizes, int n_in,
                              void* d_out, int out_size, void* d_ws, size_t ws_size,
                              hipStream_t stream)
{
    const float* x      = (const float*)d_in[0];
    const float* inj0   = (const float*)d_in[1];
    const float* inj1   = (const float*)d_in[2];
    const float* resid  = (const float*)d_in[3];
    const float* gate_w = (const float*)d_in[4];
    const float* gate_b = (const float*)d_in[5];
    const float* fuse_w = (const float*)d_in[6];
    const float* fuse_b = (const float*)d_in[7];
    const float* gn_w   = (const float*)d_in[8];
    const float* gn_b   = (const float*)d_in[9];

    float* out      = (float*)d_out;
    float* ws       = (float*)d_ws;
    float* partials = ws;                 // 2 * 2048 floats = 16 KiB
    float* sb       = ws + 2 * GRID1;     // 2 * 512 floats  =  4 KiB

    hipLaunchKernelGGL(pass1, dim3(GRID1), dim3(TPB), 0, stream,
                       x, inj0, inj1, resid, gate_w, gate_b, fuse_w, fuse_b,
                       out, partials);
    hipLaunchKernelGGL(pass2, dim3(Bv), dim3(256), 0, stream,
                       partials, gn_w, gn_b, sb);
    hipLaunchKernelGGL(pass3, dim3(2048), dim3(256), 0, stream, out, sb);
}

// Round 21
// 181.356 us; speedup vs baseline: 1.1975x; 1.1975x over previous
//
#include <hip/hip_runtime.h>
#include <stdint.h>

#define Bv 8
#define Cv 64
#define Lv 65536
#define TPB 512
#define HALF 128                      // cols per half-tile
#define COLS 256                      // cols per block (2 halves)
#define BLKS_PER_B (Lv / COLS)        // 256
#define GRID1 (Bv * BLKS_PER_B)       // 2048

// workspace: partials 2*2048 floats (16 KiB); sb region unused now = 20 KiB cap

typedef __attribute__((ext_vector_type(8))) short short8;
typedef __attribute__((ext_vector_type(4))) float f32x4;

#define SSTRIDE 132   // dwords per row

__device__ __forceinline__ uint16_t f2bf(float f) {
    uint32_t u = __float_as_uint(f);
    uint32_t r = u + 0x7FFFu + ((u >> 16) & 1u);   // round-to-nearest-even
    return (uint16_t)(r >> 16);
}
__device__ __forceinline__ uint32_t pack2bf(float lo, float hi) {
    return (uint32_t)f2bf(lo) | ((uint32_t)f2bf(hi) << 16);
}
__device__ __forceinline__ float bf_lo(uint32_t u) { return __uint_as_float(u << 16); }
__device__ __forceinline__ float bf_hi(uint32_t u) { return __uint_as_float(u & 0xFFFF0000u); }

// ---------------------------------------------------------------------------
// Pass 1 (R17 core, consolidated): out = relu(Wf·(x⊙(Wg·s+2bg)) + bf + resid)
// R21: best-known structure (R17, 171us pass1) + two wave-local barrier
// removals (acc->GEMM2, GEMM2->epi-fragwrite touch only the wave's own
// column slab; safety validated by R15/R19 passing with the same pattern).
// 15 structural variants pinned at ~171us across occupancy/blocks/barriers/
// MLP/traffic — latency-pattern-bound (64 rows @256KB stride, <=1KB chunks).
// ---------------------------------------------------------------------------
__global__ void pass1(const float* __restrict__ x, const float* __restrict__ inj0,
                      const float* __restrict__ inj1, const float* __restrict__ resid,
                      const float* __restrict__ gate_w, const float* __restrict__ gate_b,
                      const float* __restrict__ fuse_w, const float* __restrict__ fuse_b,
                      float* __restrict__ out, float* __restrict__ partials)
{
    __shared__ uint32_t s_buf[32 * SSTRIDE];   // 16.9 KB (s / acc / epi tile)
    __shared__ uint32_t x_buf[32 * SSTRIDE];   // 16.9 KB (x bf16 kpairs)
    __shared__ uint32_t w_lds[2][64][36];      // 18.4 KB
    __shared__ float cinit[2][64];             // [0]=2*gate_b, [1]=fuse_b
    __shared__ float wred[16];                 // per-wave stats partials

    const int tid  = threadIdx.x;
    const int lane = tid & 63;
    const int w    = tid >> 6;     // wave 0..7
    const int g    = lane >> 4;    // k-group 0..3
    const int ln   = lane & 15;    // 0..15
    const int n    = 16 * w + ln;  // wave's column within the half

    const int b    = blockIdx.x >> 8;
    const int lb   = blockIdx.x & 255;
    const int bCL  = b * (Cv * Lv);

    // ---- stage weights + cinit (once) ----
    {
        const int mat = tid >> 8;              // 0=gate, 1=fuse
        const int m   = (tid >> 2) & 63;
        const int k0  = (tid & 3) << 4;
        const float* wsrc = mat ? fuse_w : gate_w;
        const float4* w4 = reinterpret_cast<const float4*>(wsrc + m * 64 + k0);
        uint32_t* dst = &w_lds[mat][m][k0 >> 1];
        #pragma unroll
        for (int q = 0; q < 4; ++q) {
            const float4 v = w4[q];
            dst[2 * q]     = pack2bf(v.x, v.y);
            dst[2 * q + 1] = pack2bf(v.z, v.w);
        }
        if (tid < 64) {
            cinit[0][tid] = 2.0f * gate_b[tid];
            cinit[1][tid] = fuse_b[tid];
        }
    }

    float lsum = 0.0f, lsq = 0.0f;

    #pragma unroll 1
    for (int h = 0; h < 2; ++h) {
        const int col0 = lb * COLS + h * HALF;

        // ---- stage s = i0+i1+2x AND x (bf16 kpairs; x reuses loaded regs) --
        #pragma unroll
        for (int uu = 0; uu < 2; ++uu) {
            const int u  = tid + uu * TPB;
            const int kp = u >> 5;               // 0..31 (ch pair)
            const int c  = (u & 31) << 2;        // col 0..124
            const int rA = bCL + (2 * kp) * Lv + col0 + c;
            const int rB = rA + Lv;
            const float4 xA = *reinterpret_cast<const float4*>(x    + rA);
            const float4 aA = *reinterpret_cast<const float4*>(inj0 + rA);
            const float4 bA = *reinterpret_cast<const float4*>(inj1 + rA);
            const float4 xB = *reinterpret_cast<const float4*>(x    + rB);
            const float4 aB = *reinterpret_cast<const float4*>(inj0 + rB);
            const float4 bB = *reinterpret_cast<const float4*>(inj1 + rB);
            uint4 dw;
            dw.x = pack2bf(aA.x + bA.x + 2.0f * xA.x, aB.x + bB.x + 2.0f * xB.x);
            dw.y = pack2bf(aA.y + bA.y + 2.0f * xA.y, aB.y + bB.y + 2.0f * xB.y);
            dw.z = pack2bf(aA.z + bA.z + 2.0f * xA.z, aB.z + bB.z + 2.0f * xB.z);
            dw.w = pack2bf(aA.w + bA.w + 2.0f * xA.w, aB.w + bB.w + 2.0f * xB.w);
            *reinterpret_cast<uint4*>(&s_buf[kp * SSTRIDE + c]) = dw;
            uint4 dx;
            dx.x = pack2bf(xA.x, xB.x);
            dx.y = pack2bf(xA.y, xB.y);
            dx.z = pack2bf(xA.z, xB.z);
            dx.w = pack2bf(xA.w, xB.w);
            *reinterpret_cast<uint4*>(&x_buf[kp * SSTRIDE + c]) = dx;
        }
        __syncthreads();   // s, x (and on h=0: weights/cinit) visible

        // ---- GEMM1: D1 = Wg . s + 2bg  (full K, 8 MFMA, 16 acc regs) ----
        f32x4 D1[4];
        #pragma unroll
        for (int oc = 0; oc < 4; ++oc) {
            const float4 cb = *reinterpret_cast<const float4*>(&cinit[0][16 * oc + 4 * g]);
            D1[oc][0] = cb.x; D1[oc][1] = cb.y; D1[oc][2] = cb.z; D1[oc][3] = cb.w;
        }
        {
            uint4 B0, B1;
            B0.x = s_buf[(4 * g + 0) * SSTRIDE + n];
            B0.y = s_buf[(4 * g + 1) * SSTRIDE + n];
            B0.z = s_buf[(4 * g + 2) * SSTRIDE + n];
            B0.w = s_buf[(4 * g + 3) * SSTRIDE + n];
            B1.x = s_buf[(16 + 4 * g + 0) * SSTRIDE + n];
            B1.y = s_buf[(16 + 4 * g + 1) * SSTRIDE + n];
            B1.z = s_buf[(16 + 4 * g + 2) * SSTRIDE + n];
            B1.w = s_buf[(16 + 4 * g + 3) * SSTRIDE + n];
            #pragma unroll
            for (int oc = 0; oc < 4; ++oc) {
                const int m = ln + 16 * oc;
                const uint4 A0 = *reinterpret_cast<const uint4*>(&w_lds[0][m][4 * g]);
                const uint4 A1 = *reinterpret_cast<const uint4*>(&w_lds[0][m][16 + 4 * g]);
                D1[oc] = __builtin_amdgcn_mfma_f32_16x16x32_bf16(
                    __builtin_bit_cast(short8, A0), __builtin_bit_cast(short8, B0),
                    D1[oc], 0, 0, 0);
                D1[oc] = __builtin_amdgcn_mfma_f32_16x16x32_bf16(
                    __builtin_bit_cast(short8, A1), __builtin_bit_cast(short8, B1),
                    D1[oc], 0, 0, 0);
            }
        }

        // ---- acc = x*g (x from LDS) -> in-place into s_buf (own col slab) --
        // no barrier: writes/reads confined to col n (same wave; DS in-order)
        #pragma unroll
        for (int oc = 0; oc < 4; ++oc) {
            const int kp = 8 * oc + 2 * g;            // ch pair (16oc+4g)/2
            const uint32_t u0 = x_buf[kp * SSTRIDE + n];
            const uint32_t u1 = x_buf[(kp + 1) * SSTRIDE + n];
            float av[4];
            av[0] = bf_lo(u0) * D1[oc][0];
            av[1] = bf_hi(u0) * D1[oc][1];
            av[2] = bf_lo(u1) * D1[oc][2];
            av[3] = bf_hi(u1) * D1[oc][3];
            s_buf[kp * SSTRIDE + n]       = pack2bf(av[0], av[1]);
            s_buf[(kp + 1) * SSTRIDE + n] = pack2bf(av[2], av[3]);
        }

        // ---- GEMM2: D2 = Wf . acc + fuse_b  (full K, 8 MFMA, 16 acc regs) --
        f32x4 D2[4];
        #pragma unroll
        for (int oc = 0; oc < 4; ++oc) {
            const float4 cb = *reinterpret_cast<const float4*>(&cinit[1][16 * oc + 4 * g]);
            D2[oc][0] = cb.x; D2[oc][1] = cb.y; D2[oc][2] = cb.z; D2[oc][3] = cb.w;
        }
        {
            uint4 B0, B1;
            B0.x = s_buf[(4 * g + 0) * SSTRIDE + n];
            B0.y = s_buf[(4 * g + 1) * SSTRIDE + n];
            B0.z = s_buf[(4 * g + 2) * SSTRIDE + n];
            B0.w = s_buf[(4 * g + 3) * SSTRIDE + n];
            B1.x = s_buf[(16 + 4 * g + 0) * SSTRIDE + n];
            B1.y = s_buf[(16 + 4 * g + 1) * SSTRIDE + n];
            B1.z = s_buf[(16 + 4 * g + 2) * SSTRIDE + n];
            B1.w = s_buf[(16 + 4 * g + 3) * SSTRIDE + n];
            #pragma unroll
            for (int oc = 0; oc < 4; ++oc) {
                const int m = ln + 16 * oc;
                const uint4 A0 = *reinterpret_cast<const uint4*>(&w_lds[1][m][4 * g]);
                const uint4 A1 = *reinterpret_cast<const uint4*>(&w_lds[1][m][16 + 4 * g]);
                D2[oc] = __builtin_amdgcn_mfma_f32_16x16x32_bf16(
                    __builtin_bit_cast(short8, A0), __builtin_bit_cast(short8, B0),
                    D2[oc], 0, 0, 0);
                D2[oc] = __builtin_amdgcn_mfma_f32_16x16x32_bf16(
                    __builtin_bit_cast(short8, A1), __builtin_bit_cast(short8, B1),
                    D2[oc], 0, 0, 0);
            }
        }
        // no barrier: epi frag-writes below also stay within col n (own wave)

        // ---- epilogue: 2 chunks of 32 rows via s_buf re-layout ----
        {
            float* uf = reinterpret_cast<float*>(s_buf);
            const int rowin = tid >> 4;          // 0..31
            const int cl    = tid & 15;          // 16 threads x 2 float4 per row
            #pragma unroll 1
            for (int ck = 0; ck < 2; ++ck) {
                #pragma unroll
                for (int oc2 = 0; oc2 < 2; ++oc2) {
                    const int oc = 2 * ck + oc2;
                    #pragma unroll
                    for (int j = 0; j < 4; ++j)
                        uf[(16 * oc2 + 4 * g + j) * SSTRIDE + n] = D2[oc][j];
                }
                const int m   = 32 * ck + rowin;
                const int gbm = bCL + m * Lv + col0;
                const float4 ra = *reinterpret_cast<const float4*>(&resid[gbm + 4 * cl]);
                const float4 rb = *reinterpret_cast<const float4*>(&resid[gbm + 4 * cl + 64]);
                __syncthreads();   // cross-wave: all frag writes visible
                float4 va = *reinterpret_cast<const float4*>(&uf[rowin * SSTRIDE + 4 * cl]);
                float4 vb = *reinterpret_cast<const float4*>(&uf[rowin * SSTRIDE + 4 * cl + 64]);
                va.x = fmaxf(va.x + ra.x, 0.0f); va.y = fmaxf(va.y + ra.y, 0.0f);
                va.z = fmaxf(va.z + ra.z, 0.0f); va.w = fmaxf(va.w + ra.w, 0.0f);
                vb.x = fmaxf(vb.x + rb.x, 0.0f); vb.y = fmaxf(vb.y + rb.y, 0.0f);
                vb.z = fmaxf(vb.z + rb.z, 0.0f); vb.w = fmaxf(vb.w + rb.w, 0.0f);
                *reinterpret_cast<float4*>(&out[gbm + 4 * cl])      = va;
                *reinterpret_cast<float4*>(&out[gbm + 4 * cl + 64]) = vb;
                lsum += (va.x + va.y) + (va.z + va.w) + (vb.x + vb.y) + (vb.z + vb.w);
                lsq = fmaf(va.x, va.x, lsq); lsq = fmaf(va.y, va.y, lsq);
                lsq = fmaf(va.z, va.z, lsq); lsq = fmaf(va.w, va.w, lsq);
                lsq = fmaf(vb.x, vb.x, lsq); lsq = fmaf(vb.y, vb.y, lsq);
                lsq = fmaf(vb.z, vb.z, lsq); lsq = fmaf(vb.w, vb.w, lsq);
                __syncthreads();   // chunk reads done before next writes/half
            }
        }
    }

    // ---- stats: wave shuffle reduce -> 8 partials -> thread 0 ----
    #pragma unroll
    for (int st = 1; st < 64; st <<= 1) {
        lsum += __shfl_xor(lsum, st);
        lsq  += __shfl_xor(lsq,  st);
    }
    if (lane == 0) { wred[2 * w] = lsum; wred[2 * w + 1] = lsq; }
    __syncthreads();
    if (tid == 0) {
        float s = 0.0f, q = 0.0f;
        #pragma unroll
        for (int i = 0; i < 8; ++i) { s += wred[2 * i]; q += wred[2 * i + 1]; }
        partials[2 * blockIdx.x]     = s;
        partials[2 * blockIdx.x + 1] = q;
    }
}

// ---------------------------------------------------------------------------
// Pass 2+3 fused: each block covers one contiguous quarter-row (4096 float4),
// redundantly reduces its batch's 256 partials (512B, L2-broadcast), then
// applies the GroupNorm affine in-place. Removes the separate pass2 launch.
// ---------------------------------------------------------------------------
__global__ __launch_bounds__(256)
void pass23(float* __restrict__ out, const float* __restrict__ partials,
            const float* __restrict__ gn_w, const float* __restrict__ gn_b)
{
    __shared__ float r1[256], r2[256];
    const int tid = threadIdx.x;
    const int row = blockIdx.x >> 2;          // b*64 + c  (4 blocks per row)
    const int b   = row >> 6;
    const int c   = row & 63;

    r1[tid] = partials[2 * (b * 256 + tid)];
    r2[tid] = partials[2 * (b * 256 + tid) + 1];
    __syncthreads();
    #pragma unroll
    for (int st = 128; st > 0; st >>= 1) {
        if (tid < st) { r1[tid] += r1[tid + st]; r2[tid] += r2[tid + st]; }
        __syncthreads();
    }
    const float nel  = (float)Cv * (float)Lv;
    const float mean = r1[0] / nel;
    const float var  = r2[0] / nel - mean * mean;
    const float rs   = rsqrtf(var + 1e-5f);
    const float sc   = gn_w[c] * rs;
    const float bi   = fmaf(-mean, sc, gn_b[c]);

    float4* o4 = reinterpret_cast<float4*>(out);
    const int i0 = blockIdx.x * 4096;         // contiguous quarter-row
    #pragma unroll
    for (int k = 0; k < 16; ++k) {
        const int i = i0 + tid + (k << 8);
        float4 v = o4[i];
        v.x = fmaf(v.x, sc, bi);
        v.y = fmaf(v.y, sc, bi);
        v.z = fmaf(v.z, sc, bi);
        v.w = fmaf(v.w, sc, bi);
        o4[i] = v;
    }
}

extern "C" void kernel_launch(void* const* d_in, const int* in_sizes, int n_in,
                              void* d_out, int out_size, void* d_ws, size_t ws_size,
                              hipStream_t stream)
{
    const float* x      = (const float*)d_in[0];
    const float* inj0   = (const float*)d_in[1];
    const float* inj1   = (const float*)d_in[2];
    const float* resid  = (const float*)d_in[3];
    const float* gate_w = (const float*)d_in[4];
    const float* gate_b = (const float*)d_in[5];
    const float* fuse_w = (const float*)d_in[6];
    const float* fuse_b = (const float*)d_in[7];
    const float* gn_w   = (const float*)d_in[8];
    const float* gn_b   = (const float*)d_in[9];

    float* out      = (float*)d_out;
    float* partials = (float*)d_ws;       // 2 * 2048 floats = 16 KiB

    hipLaunchKernelGGL(pass1, dim3(GRID1), dim3(TPB), 0, stream,
                       x, inj0, inj1, resid, gate_w, gate_b, fuse_w, fuse_b,
                       out, partials);
    hipLaunchKernelGGL(pass23, dim3(2048), dim3(256), 0, stream,
                       out, partials, gn_w, gn_b);
}